// Round 10
// baseline (232.827 us; speedup 1.0000x reference)
//
#include <hip/hip_runtime.h>
#include <cstdint>
#include <cstddef>

#define N_NODES 50000
#define N_EDGES 800000
#define ROWS_PAD 50048  // 3128 tiles * 16 rows; pad rows: deg 0, stores guarded
#define ZROW 50000      // dedicated all-zero fp8 row for ragged-degree padding
#define BUCKET_CAP 64   // Poisson(16) max degree over 50K nodes ~45; P(>64) ~ 1e-18

typedef _Float16 f16;
typedef _Float16 f16x2 __attribute__((ext_vector_type(2)));
typedef _Float16 f16x8 __attribute__((ext_vector_type(8)));
typedef float f32x2 __attribute__((ext_vector_type(2)));
typedef float f32x4 __attribute__((ext_vector_type(4)));
typedef float fx4 __attribute__((ext_vector_type(4)));          // for NT loads (not HIP_vector_type)
typedef unsigned int u32x2 __attribute__((ext_vector_type(2))); // for NT stores
typedef unsigned short us4 __attribute__((ext_vector_type(4)));

// ---------------- fused preprocessing (one dispatch, block-range split) --------
// Fill is dst-range partitioned 16-way (blockIdx&15): each range-group's bucket
// writes stay in a 0.4 MB slice -> lines dirty once. Round-8 evidence: the
// concurrently-fused converts streamed ~45 MB through the same L2s and evicted
// the bucket slices (WRITE 50 MB vs 26 logical) -> all streaming traffic in
// this kernel is now NON-TEMPORAL so the bucket slices stay L2-resident.

#define NRANGE 16
#define EPT 16
#define CHUNK (256 * EPT)                       // 4096 edges
#define NCHUNK ((N_EDGES + CHUNK - 1) / CHUNK)  // 196
#define NB_FILL (NCHUNK * NRANGE)               // 3136
#define NB_CX 3125                              // 50000*16 threads, 8 elems each
#define NB_CW 192                               // (128*256 + 64*256) / 256
#define RANGE_SZ (N_NODES / NRANGE)             // 3125

__global__ __launch_bounds__(256) void preprocess_kernel(
    const int* __restrict__ edge, int* __restrict__ cnt, unsigned short* __restrict__ bucket,
    const float* __restrict__ x, f16* __restrict__ X16, unsigned char* __restrict__ X8,
    unsigned char* __restrict__ H8,
    const float* __restrict__ Wl1, const float* __restrict__ Wr1,
    const float* __restrict__ Wl2, const float* __restrict__ Wr2,
    f16* __restrict__ Wc1, f16* __restrict__ Wc2) {
  const int b = blockIdx.x;
  const int tid = threadIdx.x;
  if (b < NB_FILL) {
    const int r = b & (NRANGE - 1), chunk = b >> 4;
    const int lo = r * RANGE_SZ, hi = lo + RANGE_SZ;
    const int base = chunk * CHUNK + tid;
    #pragma unroll
    for (int i = 0; i < EPT; ++i) {
      const int e = base + i * 256;
      if (e < N_EDGES) {
        const int dst = __builtin_nontemporal_load(edge + N_EDGES + e);
        if (dst >= lo && dst < hi) {
          const int src = __builtin_nontemporal_load(edge + e);
          const int pos = atomicAdd(&cnt[dst], 1);
          if (pos < BUCKET_CAP) bucket[(size_t)dst * BUCKET_CAP + pos] = (unsigned short)src;
        }
      }
    }
  } else if (b < NB_FILL + NB_CX) {
    const int idx = (b - NB_FILL) * 256 + tid;  // < 800000 exact
    const int row = idx >> 4, c8 = idx & 15;
    const fx4 v0 =
        __builtin_nontemporal_load(reinterpret_cast<const fx4*>(x + (size_t)row * 128 + c8 * 8));
    const fx4 v1 = __builtin_nontemporal_load(
        reinterpret_cast<const fx4*>(x + (size_t)row * 128 + c8 * 8 + 4));
    f16x8 o;
    o[0] = (f16)v0[0]; o[1] = (f16)v0[1]; o[2] = (f16)v0[2]; o[3] = (f16)v0[3];
    o[4] = (f16)v1[0]; o[5] = (f16)v1[1]; o[6] = (f16)v1[2]; o[7] = (f16)v1[3];
    __builtin_nontemporal_store(o, reinterpret_cast<f16x8*>(X16 + (size_t)row * 128 + c8 * 8));
    // fp8 e4m3 copy for the gather table (mean path only; root path stays f16)
    u32x2 p;
    int w = __builtin_amdgcn_cvt_pk_fp8_f32(v0[0], v0[1], 0, false);
    w = __builtin_amdgcn_cvt_pk_fp8_f32(v0[2], v0[3], w, true);
    p[0] = (unsigned int)w;
    w = __builtin_amdgcn_cvt_pk_fp8_f32(v1[0], v1[1], 0, false);
    w = __builtin_amdgcn_cvt_pk_fp8_f32(v1[2], v1[3], w, true);
    p[1] = (unsigned int)w;
    __builtin_nontemporal_store(p, reinterpret_cast<u32x2*>(X8 + (size_t)row * 128 + c8 * 8));
  } else if (b < NB_FILL + NB_CX + NB_CW) {
    const int idx = (b - NB_FILL - NB_CX) * 256 + tid;  // < 49152 exact
    // Wc[n][k] = k<128 ? Wl[n][k] : Wr[n][k-128]
    if (idx < 128 * 256) {
      const int n = idx >> 8, k = idx & 255;
      Wc1[idx] = (f16)((k < 128) ? Wl1[n * 128 + k] : Wr1[n * 128 + (k - 128)]);
    } else {
      const int j = idx - 128 * 256;
      const int n = j >> 8, k = j & 255;
      Wc2[j] = (f16)((k < 128) ? Wl2[n * 128 + k] : Wr2[n * 128 + (k - 128)]);
    }
  } else {
    // zero both ZROW fp8 rows (gather padding target; fp8 zero = 0x00)
    if (tid < 32)
      reinterpret_cast<unsigned int*>(X8 + (size_t)ZROW * 128)[tid] = 0u;
    else if (tid < 64)
      reinterpret_cast<unsigned int*>(H8 + (size_t)ZROW * 128)[tid - 32] = 0u;
  }
}

// ---------------- aggregate: 4 nodes/wave (16/block) -> LDS means --------------
// fp8 gather: per instr 64 lanes x 8B = 4 full 128B neighbor rows (one L2 line
// each); 16 loads (32 VGPRs) genuinely in flight. Decode v_cvt_pk_f32_fp8,
// accumulate fp32, write means to LDS as f16. M rows padded to 136 f16 ->
// 2-way bank aliasing only (free, m136).

__device__ __forceinline__ void aggregate4_to_lds(
    const unsigned char* __restrict__ F8, const int* __restrict__ cnt,
    const unsigned short* __restrict__ bucket,
    f16 (*M)[136], int wid, int lane) {
  const int quad = lane >> 4, l16 = lane & 15;
  const int nb = blockIdx.x * 16 + wid * 4;
  const int node = nb + quad;
  const int dv = (lane < 4) ? cnt[nb + lane] : 0;
  const int dq = __shfl(dv, quad, 64);
  const int dqc = min(dq, BUCKET_CAP);
  int md = max(max(__shfl(dv, 0, 64), __shfl(dv, 1, 64)),
               max(__shfl(dv, 2, 64), __shfl(dv, 3, 64)));
  md = min(md, BUCKET_CAP);
  // lane l16 of quad q holds bucket slots [4*l16, 4*l16+4) of node nb+q
  const us4 b4 = *reinterpret_cast<const us4*>(bucket + (size_t)node * BUCKET_CAP + l16 * 4);
  float acc[8];
  #pragma unroll
  for (int c = 0; c < 8; ++c) acc[c] = 0.f;
  const unsigned char* Fsrc = F8 + l16 * 8;
  for (int j = 0; j < md; j += 16) {
    u32x2 v[16];
    #pragma unroll
    for (int k = 0; k < 16; ++k) {
      const int slot = j + k;  // j%16==0 -> slot&3 == k&3
      const int idx = __shfl((int)b4[k & 3], quad * 16 + (slot >> 2), 64);
      const int row = (slot < dqc) ? idx : ZROW;  // ZROW zeroed
      v[k] = *reinterpret_cast<const u32x2*>(Fsrc + (size_t)row * 128);
    }
    #pragma unroll
    for (int k = 0; k < 16; ++k) {
      const f32x2 f0 = __builtin_amdgcn_cvt_pk_f32_fp8((int)v[k][0], false);
      const f32x2 f1 = __builtin_amdgcn_cvt_pk_f32_fp8((int)v[k][0], true);
      const f32x2 f2 = __builtin_amdgcn_cvt_pk_f32_fp8((int)v[k][1], false);
      const f32x2 f3 = __builtin_amdgcn_cvt_pk_f32_fp8((int)v[k][1], true);
      acc[0] += f0[0]; acc[1] += f0[1]; acc[2] += f1[0]; acc[3] += f1[1];
      acc[4] += f2[0]; acc[5] += f2[1]; acc[6] += f3[0]; acc[7] += f3[1];
    }
  }
  const float inv = 1.0f / (float)(dq > 0 ? dq : 1);
  f16x8 o;
  #pragma unroll
  for (int c = 0; c < 8; ++c) o[c] = (f16)(acc[c] * inv);
  *reinterpret_cast<f16x8*>(&M[wid * 4 + quad][l16 * 8]) = o;
}

// ---------------- layer 1: aggregate + gemm  H = relu([mean|x] * Wc1^T + b) ----
// 16-row tile, grid 3128 (12.2 blocks/CU demand vs 8/CU slot limit -> sustained
// full occupancy; round-8 evidence: 32-row/1564-block grid averaged 37%).
// Wave w: all 16 rows, N-tiles [2w, 2w+2). K=256: k<128 A-frag from LDS means,
// k>=128 from X16 (f16). D: row = quad*4+r, col = lane&15.

__global__ __launch_bounds__(256, 4) void layer1_kernel(
    const f16* __restrict__ X16, const unsigned char* __restrict__ X8,
    const int* __restrict__ cnt, const unsigned short* __restrict__ bucket,
    const f16* __restrict__ Wc, const float* __restrict__ bias,
    f16* __restrict__ H16, unsigned char* __restrict__ H8) {
  __shared__ f16 M[16][136];
  const int wid = threadIdx.x >> 6, lane = threadIdx.x & 63;
  const int quad = lane >> 4, l16 = lane & 15;
  aggregate4_to_lds(X8, cnt, bucket, M, wid, lane);
  __syncthreads();
  const int row0 = blockIdx.x * 16;
  f32x4 acc[2];
  #pragma unroll
  for (int t = 0; t < 2; ++t) acc[t] = (f32x4){0.f, 0.f, 0.f, 0.f};
  const f16x8* Wb = reinterpret_cast<const f16x8*>(Wc) + quad;
  const f16* Xrow = X16 + (size_t)(row0 + l16) * 128 + quad * 8;
  #pragma unroll
  for (int s = 0; s < 8; ++s) {
    const f16x8 a = (s < 4)
        ? *reinterpret_cast<const f16x8*>(&M[l16][quad * 8 + s * 32])
        : *reinterpret_cast<const f16x8*>(Xrow + (s - 4) * 32);
    #pragma unroll
    for (int t = 0; t < 2; ++t) {
      const int u = wid * 2 + t;
      const f16x8 bb = Wb[(u * 16 + l16) * 32 + s * 4];
      acc[t] = __builtin_amdgcn_mfma_f32_16x16x32_f16(a, bb, acc[t], 0, 0, 0);
    }
  }
  #pragma unroll
  for (int t = 0; t < 2; ++t) {
    const int col = (wid * 2 + t) * 16 + l16;
    const float bv = bias[col];
    #pragma unroll
    for (int r = 0; r < 4; ++r) {
      const int row = row0 + quad * 4 + r;
      if (row < N_NODES) {
        const float vv = fmaxf(acc[t][r] + bv, 0.f);
        H16[(size_t)row * 128 + col] = (f16)vv;
        const int p = __builtin_amdgcn_cvt_pk_fp8_f32(vv, vv, 0, false);
        H8[(size_t)row * 128 + col] = (unsigned char)(p & 0xFF);
      }
    }
  }
}

// ---------------- layer 2: aggregate + gemm + relu + log_softmax ---------------
// 16-row tile: wave w owns N-tile w (16 cols). Softmax row spans all 4 waves ->
// LDS partial max/sum combine (PM/PS), each wave reads all 4 partials.

__global__ __launch_bounds__(256, 4) void layer2_kernel(
    const f16* __restrict__ H16, const unsigned char* __restrict__ H8,
    const int* __restrict__ cnt, const unsigned short* __restrict__ bucket,
    const f16* __restrict__ Wc, const float* __restrict__ bias,
    float* __restrict__ out) {
  __shared__ f16 M[16][136];
  __shared__ float PM[4][16], PS[4][16];
  const int wid = threadIdx.x >> 6, lane = threadIdx.x & 63;
  const int quad = lane >> 4, l16 = lane & 15;
  aggregate4_to_lds(H8, cnt, bucket, M, wid, lane);
  __syncthreads();
  const int row0 = blockIdx.x * 16;
  f32x4 acc = (f32x4){0.f, 0.f, 0.f, 0.f};
  const f16x8* Wb = reinterpret_cast<const f16x8*>(Wc) + quad;
  const f16* Hrow = H16 + (size_t)(row0 + l16) * 128 + quad * 8;
  #pragma unroll
  for (int s = 0; s < 8; ++s) {
    const f16x8 a = (s < 4)
        ? *reinterpret_cast<const f16x8*>(&M[l16][quad * 8 + s * 32])
        : *reinterpret_cast<const f16x8*>(Hrow + (s - 4) * 32);
    const f16x8 bb = Wb[(wid * 16 + l16) * 32 + s * 4];
    acc = __builtin_amdgcn_mfma_f32_16x16x32_f16(a, bb, acc, 0, 0, 0);
  }
  const float bv = bias[wid * 16 + l16];
  float v[4], pm[4], ps[4];
  #pragma unroll
  for (int r = 0; r < 4; ++r) {
    v[r] = fmaxf(acc[r] + bv, 0.f);
    float m = v[r];
    #pragma unroll
    for (int off = 1; off < 16; off <<= 1) m = fmaxf(m, __shfl_xor(m, off, 64));
    float s = __expf(v[r] - m);
    #pragma unroll
    for (int off = 1; off < 16; off <<= 1) s += __shfl_xor(s, off, 64);
    pm[r] = m;
    ps[r] = s;
  }
  if (l16 == 0) {
    #pragma unroll
    for (int r = 0; r < 4; ++r) {
      PM[wid][quad * 4 + r] = pm[r];
      PS[wid][quad * 4 + r] = ps[r];
    }
  }
  __syncthreads();
  #pragma unroll
  for (int r = 0; r < 4; ++r) {
    const int idx = quad * 4 + r;
    const float m0 = PM[0][idx], m1 = PM[1][idx], m2 = PM[2][idx], m3 = PM[3][idx];
    const float mt = fmaxf(fmaxf(m0, m1), fmaxf(m2, m3));
    const float st = PS[0][idx] * __expf(m0 - mt) + PS[1][idx] * __expf(m1 - mt) +
                     PS[2][idx] * __expf(m2 - mt) + PS[3][idx] * __expf(m3 - mt);
    const float ls = mt + __logf(st);
    const int row = row0 + idx;
    if (row < N_NODES)
      out[(size_t)row * 64 + wid * 16 + l16] = v[r] - ls;
  }
}

// ---------------- launch ----------------

extern "C" void kernel_launch(void* const* d_in, const int* in_sizes, int n_in,
                              void* d_out, int out_size, void* d_ws, size_t ws_size,
                              hipStream_t stream) {
  const float* x   = (const float*)d_in[0];
  const int* edge  = (const int*)d_in[1];  // [2][N_EDGES] int32
  const float* Wl1 = (const float*)d_in[2];
  const float* bl1 = (const float*)d_in[3];
  const float* Wr1 = (const float*)d_in[4];
  const float* Wl2 = (const float*)d_in[5];
  const float* bl2 = (const float*)d_in[6];
  const float* Wr2 = (const float*)d_in[7];
  float* out = (float*)d_out;

  char* ws = (char*)d_ws;
  size_t off = 0;
  auto alloc = [&](size_t bytes) -> char* {
    char* p = ws + off;
    off = (off + bytes + 255) & ~(size_t)255;
    return p;
  };
  int* cnt               = (int*)alloc((size_t)ROWS_PAD * 4);
  unsigned short* bucket = (unsigned short*)alloc((size_t)ROWS_PAD * BUCKET_CAP * 2);
  f16* X16           = (f16*)alloc((size_t)ROWS_PAD * 128 * 2);  // x f16 (root path)
  f16* H16           = (f16*)alloc((size_t)ROWS_PAD * 128 * 2);  // h f16 (root path)
  unsigned char* X8  = (unsigned char*)alloc((size_t)ROWS_PAD * 128);  // x fp8 (gather)
  unsigned char* H8  = (unsigned char*)alloc((size_t)ROWS_PAD * 128);  // h fp8 (gather)
  f16* Wc1           = (f16*)alloc((size_t)128 * 256 * 2);  // [Wl1 | Wr1] rows
  f16* Wc2           = (f16*)alloc((size_t)64 * 256 * 2);   // [Wl2 | Wr2] rows

  hipMemsetAsync(cnt, 0, (size_t)ROWS_PAD * 4, stream);

  preprocess_kernel<<<NB_FILL + NB_CX + NB_CW + 1, 256, 0, stream>>>(
      edge, cnt, bucket, x, X16, X8, H8, Wl1, Wr1, Wl2, Wr2, Wc1, Wc2);

  layer1_kernel<<<ROWS_PAD / 16, 256, 0, stream>>>(X16, X8, cnt, bucket, Wc1, bl1, H16, H8);
  layer2_kernel<<<ROWS_PAD / 16, 256, 0, stream>>>(H16, H8, cnt, bucket, Wc2, bl2, out);
}

// Round 11
// 216.952 us; speedup vs baseline: 1.0732x; 1.0732x over previous
//
#include <hip/hip_runtime.h>
#include <cstdint>
#include <cstddef>

#define N_NODES 50000
#define N_EDGES 800000
#define ROWS_PAD 50048  // 3128 tiles * 16 rows; pad rows: deg 0, stores guarded
#define ZROW 50000      // dedicated all-zero fp8 row for ragged-degree padding
#define BUCKET_CAP 64   // Poisson(16) max degree over 50K nodes ~45; P(>64) ~ 1e-18

typedef _Float16 f16;
typedef _Float16 f16x2 __attribute__((ext_vector_type(2)));
typedef _Float16 f16x8 __attribute__((ext_vector_type(8)));
typedef float f32x2 __attribute__((ext_vector_type(2)));
typedef float f32x4 __attribute__((ext_vector_type(4)));
typedef float fx4 __attribute__((ext_vector_type(4)));
typedef unsigned int u32x2 __attribute__((ext_vector_type(2)));
typedef unsigned short us4 __attribute__((ext_vector_type(4)));

// ---------------- fused preprocessing (one dispatch, block-range split) --------
// Fill is dst-range partitioned 16-way (blockIdx&15): range r lands on XCD
// r%8 under round-robin block->XCD dispatch, so each XCD's bucket writes stay
// in a 0.8 MB slice. NO non-temporal hints anywhere: round-10 proved NT loads
// kill the L2-warm edge re-scan and NT stores evict X8 before layer1's gathers
// (+16 us total). X16 is gone entirely -- layer1 reads x fp32 roots directly.

#define NRANGE 16
#define EPT 16
#define CHUNK (256 * EPT)                       // 4096 edges
#define NCHUNK ((N_EDGES + CHUNK - 1) / CHUNK)  // 196
#define NB_FILL (NCHUNK * NRANGE)               // 3136
#define NB_CX 3125                              // 50000*16 threads, 8 fp8 each
#define NB_CW 192                               // (128*256 + 64*256) / 256
#define RANGE_SZ (N_NODES / NRANGE)             // 3125

__global__ __launch_bounds__(256) void preprocess_kernel(
    const int* __restrict__ edge, int* __restrict__ cnt, unsigned short* __restrict__ bucket,
    const float* __restrict__ x, unsigned char* __restrict__ X8, unsigned char* __restrict__ H8,
    const float* __restrict__ Wl1, const float* __restrict__ Wr1,
    const float* __restrict__ Wl2, const float* __restrict__ Wr2,
    f16* __restrict__ Wc1, f16* __restrict__ Wc2) {
  const int b = blockIdx.x;
  const int tid = threadIdx.x;
  if (b < NB_FILL) {
    const int r = b & (NRANGE - 1), chunk = b >> 4;
    const int lo = r * RANGE_SZ, hi = lo + RANGE_SZ;
    const int base = chunk * CHUNK + tid;
    #pragma unroll
    for (int i = 0; i < EPT; ++i) {
      const int e = base + i * 256;
      if (e < N_EDGES) {
        const int dst = edge[N_EDGES + e];
        if (dst >= lo && dst < hi) {
          const int src = edge[e];
          const int pos = atomicAdd(&cnt[dst], 1);
          if (pos < BUCKET_CAP) bucket[(size_t)dst * BUCKET_CAP + pos] = (unsigned short)src;
        }
      }
    }
  } else if (b < NB_FILL + NB_CX) {
    const int idx = (b - NB_FILL) * 256 + tid;  // < 800000 exact
    const int row = idx >> 4, c8 = idx & 15;
    const fx4 v0 = *reinterpret_cast<const fx4*>(x + (size_t)row * 128 + c8 * 8);
    const fx4 v1 = *reinterpret_cast<const fx4*>(x + (size_t)row * 128 + c8 * 8 + 4);
    // fp8 e4m3 gather table (mean path only; root path reads x directly)
    u32x2 p;
    int w = __builtin_amdgcn_cvt_pk_fp8_f32(v0[0], v0[1], 0, false);
    w = __builtin_amdgcn_cvt_pk_fp8_f32(v0[2], v0[3], w, true);
    p[0] = (unsigned int)w;
    w = __builtin_amdgcn_cvt_pk_fp8_f32(v1[0], v1[1], 0, false);
    w = __builtin_amdgcn_cvt_pk_fp8_f32(v1[2], v1[3], w, true);
    p[1] = (unsigned int)w;
    *reinterpret_cast<u32x2*>(X8 + (size_t)row * 128 + c8 * 8) = p;
  } else if (b < NB_FILL + NB_CX + NB_CW) {
    const int idx = (b - NB_FILL - NB_CX) * 256 + tid;  // < 49152 exact
    // Wc[n][k] = k<128 ? Wl[n][k] : Wr[n][k-128]
    if (idx < 128 * 256) {
      const int n = idx >> 8, k = idx & 255;
      Wc1[idx] = (f16)((k < 128) ? Wl1[n * 128 + k] : Wr1[n * 128 + (k - 128)]);
    } else {
      const int j = idx - 128 * 256;
      const int n = j >> 8, k = j & 255;
      Wc2[j] = (f16)((k < 128) ? Wl2[n * 128 + k] : Wr2[n * 128 + (k - 128)]);
    }
  } else {
    // zero both ZROW fp8 rows (gather padding target; fp8 zero = 0x00)
    if (tid < 32)
      reinterpret_cast<unsigned int*>(X8 + (size_t)ZROW * 128)[tid] = 0u;
    else if (tid < 64)
      reinterpret_cast<unsigned int*>(H8 + (size_t)ZROW * 128)[tid - 32] = 0u;
  }
}

// ---------------- aggregate: 4 nodes/wave (16/block) -> LDS means --------------
// fp8 gather: per instr 64 lanes x 8B = 4 full 128B neighbor rows (one L2 line
// each); 16 loads (32 VGPRs) in flight. Decode v_cvt_pk_f32_fp8, accumulate
// fp32, write means to LDS as f16. M rows padded to 136 f16 -> 2-way bank
// aliasing only (free, m136).

__device__ __forceinline__ void aggregate4_to_lds(
    const unsigned char* __restrict__ F8, const int* __restrict__ cnt,
    const unsigned short* __restrict__ bucket,
    f16 (*M)[136], int wid, int lane) {
  const int quad = lane >> 4, l16 = lane & 15;
  const int nb = blockIdx.x * 16 + wid * 4;
  const int node = nb + quad;
  const int dv = (lane < 4) ? cnt[nb + lane] : 0;
  const int dq = __shfl(dv, quad, 64);
  const int dqc = min(dq, BUCKET_CAP);
  int md = max(max(__shfl(dv, 0, 64), __shfl(dv, 1, 64)),
               max(__shfl(dv, 2, 64), __shfl(dv, 3, 64)));
  md = min(md, BUCKET_CAP);
  // lane l16 of quad q holds bucket slots [4*l16, 4*l16+4) of node nb+q
  const us4 b4 = *reinterpret_cast<const us4*>(bucket + (size_t)node * BUCKET_CAP + l16 * 4);
  float acc[8];
  #pragma unroll
  for (int c = 0; c < 8; ++c) acc[c] = 0.f;
  const unsigned char* Fsrc = F8 + l16 * 8;
  for (int j = 0; j < md; j += 16) {
    u32x2 v[16];
    #pragma unroll
    for (int k = 0; k < 16; ++k) {
      const int slot = j + k;  // j%16==0 -> slot&3 == k&3
      const int idx = __shfl((int)b4[k & 3], quad * 16 + (slot >> 2), 64);
      const int row = (slot < dqc) ? idx : ZROW;  // ZROW zeroed
      v[k] = *reinterpret_cast<const u32x2*>(Fsrc + (size_t)row * 128);
    }
    #pragma unroll
    for (int k = 0; k < 16; ++k) {
      const f32x2 f0 = __builtin_amdgcn_cvt_pk_f32_fp8((int)v[k][0], false);
      const f32x2 f1 = __builtin_amdgcn_cvt_pk_f32_fp8((int)v[k][0], true);
      const f32x2 f2 = __builtin_amdgcn_cvt_pk_f32_fp8((int)v[k][1], false);
      const f32x2 f3 = __builtin_amdgcn_cvt_pk_f32_fp8((int)v[k][1], true);
      acc[0] += f0[0]; acc[1] += f0[1]; acc[2] += f1[0]; acc[3] += f1[1];
      acc[4] += f2[0]; acc[5] += f2[1]; acc[6] += f3[0]; acc[7] += f3[1];
    }
  }
  const float inv = 1.0f / (float)(dq > 0 ? dq : 1);
  f16x8 o;
  #pragma unroll
  for (int c = 0; c < 8; ++c) o[c] = (f16)(acc[c] * inv);
  *reinterpret_cast<f16x8*>(&M[wid * 4 + quad][l16 * 8]) = o;
}

// ---------------- layer 1: aggregate + gemm  H = relu([mean|x] * Wc1^T + b) ----
// 16-row tile, grid 3128. Wave w: all 16 rows, N-tiles [2w, 2w+2). K=256:
// k<128 A-frag from LDS means, k>=128 from x (fp32, row-clamped for pad tiles,
// converted in-register). D: row = quad*4+r, col = lane&15.

__global__ __launch_bounds__(256, 4) void layer1_kernel(
    const float* __restrict__ x, const unsigned char* __restrict__ X8,
    const int* __restrict__ cnt, const unsigned short* __restrict__ bucket,
    const f16* __restrict__ Wc, const float* __restrict__ bias,
    f16* __restrict__ H16, unsigned char* __restrict__ H8) {
  __shared__ f16 M[16][136];
  const int wid = threadIdx.x >> 6, lane = threadIdx.x & 63;
  const int quad = lane >> 4, l16 = lane & 15;
  aggregate4_to_lds(X8, cnt, bucket, M, wid, lane);
  __syncthreads();
  const int row0 = blockIdx.x * 16;
  f32x4 acc[2];
  #pragma unroll
  for (int t = 0; t < 2; ++t) acc[t] = (f32x4){0.f, 0.f, 0.f, 0.f};
  const f16x8* Wb = reinterpret_cast<const f16x8*>(Wc) + quad;
  // clamp: pad rows (>=N_NODES) load row 49999 (valid memory; stores guarded)
  const float* Xrow = x + (size_t)min(row0 + l16, N_NODES - 1) * 128 + quad * 8;
  #pragma unroll
  for (int s = 0; s < 8; ++s) {
    f16x8 a;
    if (s < 4) {
      a = *reinterpret_cast<const f16x8*>(&M[l16][quad * 8 + s * 32]);
    } else {
      const fx4 a0 = *reinterpret_cast<const fx4*>(Xrow + (s - 4) * 32);
      const fx4 a1 = *reinterpret_cast<const fx4*>(Xrow + (s - 4) * 32 + 4);
      a[0] = (f16)a0[0]; a[1] = (f16)a0[1]; a[2] = (f16)a0[2]; a[3] = (f16)a0[3];
      a[4] = (f16)a1[0]; a[5] = (f16)a1[1]; a[6] = (f16)a1[2]; a[7] = (f16)a1[3];
    }
    #pragma unroll
    for (int t = 0; t < 2; ++t) {
      const int u = wid * 2 + t;
      const f16x8 bb = Wb[(u * 16 + l16) * 32 + s * 4];
      acc[t] = __builtin_amdgcn_mfma_f32_16x16x32_f16(a, bb, acc[t], 0, 0, 0);
    }
  }
  #pragma unroll
  for (int t = 0; t < 2; ++t) {
    const int col = (wid * 2 + t) * 16 + l16;
    const float bv = bias[col];
    #pragma unroll
    for (int r = 0; r < 4; ++r) {
      const int row = row0 + quad * 4 + r;
      if (row < N_NODES) {
        const float vv = fmaxf(acc[t][r] + bv, 0.f);
        H16[(size_t)row * 128 + col] = (f16)vv;
        const int p = __builtin_amdgcn_cvt_pk_fp8_f32(vv, vv, 0, false);
        H8[(size_t)row * 128 + col] = (unsigned char)(p & 0xFF);
      }
    }
  }
}

// ---------------- layer 2: aggregate + gemm + relu + log_softmax ---------------
// 16-row tile: wave w owns N-tile w (16 cols). Softmax row spans all 4 waves ->
// LDS partial max/sum combine (PM/PS), each wave reads all 4 partials.

__global__ __launch_bounds__(256, 4) void layer2_kernel(
    const f16* __restrict__ H16, const unsigned char* __restrict__ H8,
    const int* __restrict__ cnt, const unsigned short* __restrict__ bucket,
    const f16* __restrict__ Wc, const float* __restrict__ bias,
    float* __restrict__ out) {
  __shared__ f16 M[16][136];
  __shared__ float PM[4][16], PS[4][16];
  const int wid = threadIdx.x >> 6, lane = threadIdx.x & 63;
  const int quad = lane >> 4, l16 = lane & 15;
  aggregate4_to_lds(H8, cnt, bucket, M, wid, lane);
  __syncthreads();
  const int row0 = blockIdx.x * 16;
  f32x4 acc = (f32x4){0.f, 0.f, 0.f, 0.f};
  const f16x8* Wb = reinterpret_cast<const f16x8*>(Wc) + quad;
  const f16* Hrow = H16 + (size_t)(row0 + l16) * 128 + quad * 8;
  #pragma unroll
  for (int s = 0; s < 8; ++s) {
    const f16x8 a = (s < 4)
        ? *reinterpret_cast<const f16x8*>(&M[l16][quad * 8 + s * 32])
        : *reinterpret_cast<const f16x8*>(Hrow + (s - 4) * 32);
    const f16x8 bb = Wb[(wid * 16 + l16) * 32 + s * 4];
    acc = __builtin_amdgcn_mfma_f32_16x16x32_f16(a, bb, acc, 0, 0, 0);
  }
  const float bv = bias[wid * 16 + l16];
  float v[4], pm[4], ps[4];
  #pragma unroll
  for (int r = 0; r < 4; ++r) {
    v[r] = fmaxf(acc[r] + bv, 0.f);
    float m = v[r];
    #pragma unroll
    for (int off = 1; off < 16; off <<= 1) m = fmaxf(m, __shfl_xor(m, off, 64));
    float s = __expf(v[r] - m);
    #pragma unroll
    for (int off = 1; off < 16; off <<= 1) s += __shfl_xor(s, off, 64);
    pm[r] = m;
    ps[r] = s;
  }
  if (l16 == 0) {
    #pragma unroll
    for (int r = 0; r < 4; ++r) {
      PM[wid][quad * 4 + r] = pm[r];
      PS[wid][quad * 4 + r] = ps[r];
    }
  }
  __syncthreads();
  #pragma unroll
  for (int r = 0; r < 4; ++r) {
    const int idx = quad * 4 + r;
    const float m0 = PM[0][idx], m1 = PM[1][idx], m2 = PM[2][idx], m3 = PM[3][idx];
    const float mt = fmaxf(fmaxf(m0, m1), fmaxf(m2, m3));
    const float st = PS[0][idx] * __expf(m0 - mt) + PS[1][idx] * __expf(m1 - mt) +
                     PS[2][idx] * __expf(m2 - mt) + PS[3][idx] * __expf(m3 - mt);
    const float ls = mt + __logf(st);
    const int row = row0 + idx;
    if (row < N_NODES)
      out[(size_t)row * 64 + wid * 16 + l16] = v[r] - ls;
  }
}

// ---------------- launch ----------------

extern "C" void kernel_launch(void* const* d_in, const int* in_sizes, int n_in,
                              void* d_out, int out_size, void* d_ws, size_t ws_size,
                              hipStream_t stream) {
  const float* x   = (const float*)d_in[0];
  const int* edge  = (const int*)d_in[1];  // [2][N_EDGES] int32
  const float* Wl1 = (const float*)d_in[2];
  const float* bl1 = (const float*)d_in[3];
  const float* Wr1 = (const float*)d_in[4];
  const float* Wl2 = (const float*)d_in[5];
  const float* bl2 = (const float*)d_in[6];
  const float* Wr2 = (const float*)d_in[7];
  float* out = (float*)d_out;

  char* ws = (char*)d_ws;
  size_t off = 0;
  auto alloc = [&](size_t bytes) -> char* {
    char* p = ws + off;
    off = (off + bytes + 255) & ~(size_t)255;
    return p;
  };
  int* cnt               = (int*)alloc((size_t)ROWS_PAD * 4);
  unsigned short* bucket = (unsigned short*)alloc((size_t)ROWS_PAD * BUCKET_CAP * 2);
  f16* H16           = (f16*)alloc((size_t)ROWS_PAD * 128 * 2);       // h f16 (root path)
  unsigned char* X8  = (unsigned char*)alloc((size_t)ROWS_PAD * 128); // x fp8 (gather)
  unsigned char* H8  = (unsigned char*)alloc((size_t)ROWS_PAD * 128); // h fp8 (gather)
  f16* Wc1           = (f16*)alloc((size_t)128 * 256 * 2);  // [Wl1 | Wr1] rows
  f16* Wc2           = (f16*)alloc((size_t)64 * 256 * 2);   // [Wl2 | Wr2] rows

  hipMemsetAsync(cnt, 0, (size_t)ROWS_PAD * 4, stream);

  preprocess_kernel<<<NB_FILL + NB_CX + NB_CW + 1, 256, 0, stream>>>(
      edge, cnt, bucket, x, X8, H8, Wl1, Wr1, Wl2, Wr2, Wc1, Wc2);

  layer1_kernel<<<ROWS_PAD / 16, 256, 0, stream>>>(x, X8, cnt, bucket, Wc1, bl1, H16, H8);
  layer2_kernel<<<ROWS_PAD / 16, 256, 0, stream>>>(H16, H8, cnt, bucket, Wc2, bl2, out);
}